// Round 2
// baseline (784.169 us; speedup 1.0000x reference)
//
#include <hip/hip_runtime.h>

#define TT 1024
#define CC 128
#define LL 128
#define SS 257      // 2*L+1
#define BLANK 127   // C-1
#define NEG_INF (-1e30f)
#define EPSF 1e-7f

// Barrier that drains ONLY lgkmcnt (LDS), leaving global loads in flight.
// All cross-thread traffic in this kernel goes through LDS, so lgkmcnt(0)
// is sufficient for the barrier's memory-ordering obligation. __syncthreads
// would emit s_waitcnt vmcnt(0) and put the prefetch HBM latency on the
// critical path every iteration (measured: ~1730 cy/step).
__device__ __forceinline__ void barrier_lds_only() {
  asm volatile("s_waitcnt lgkmcnt(0)\n\ts_barrier" ::: "memory");
}

// One block per batch element. 256 threads (4 waves):
//   - thread tid owns lattice state s = tid; tid==255 also owns s = 256
//   - threads 0..127 also load/reduce the y_pred row (one float each)
// Per iteration: exactly one lgkm-only barrier; all LDS producers write the
// opposite buffer (rowbuf/partial/alpha double-buffered) from what the same
// iteration reads.
__global__ __launch_bounds__(256) void ctc_kernel(const int* __restrict__ yt,
                                                  const float* __restrict__ yp,
                                                  float* __restrict__ out) {
  const int b = blockIdx.x;
  const int tid = threadIdx.x;

  __shared__ float rowbuf[2][CC];     // (p + eps) for row t, double buffered
  __shared__ float partial[2][2];     // per-wave rowsum partials
  __shared__ float alpha[2][SS + 2];  // +2 front pad: speculated [s-2] in-bounds
  __shared__ int labels[LL];

  const float* P = yp + (size_t)b * (TT * CC);

  // --- prologue: prefetch rows 0..3 into registers, stage row 0 to LDS ---
  float v[4];
  if (tid < CC) {
#pragma unroll
    for (int j = 0; j < 4; ++j) v[j] = P[j * CC + tid] + EPSF;
    rowbuf[0][tid] = v[0];
    float x = v[0];
#pragma unroll
    for (int off = 32; off > 0; off >>= 1) x += __shfl_down(x, off);
    if ((tid & 63) == 0) partial[0][tid >> 6] = x;
    v[0] = P[4 * CC + tid] + EPSF;  // refill slot 0 with row 4
  }
  if (tid < LL) labels[tid] = yt[b * LL + tid];
  __syncthreads();  // once, prologue only

  // --- per-thread lattice-state constants ---
  const int s = tid;
  const bool has2 = (tid == 255);  // also owns s=256 (blank, no skip)
  int ext = BLANK;                 // even states are blank
  int skip = 0;
  if (s & 1) {
    const int k = s >> 1;
    ext = labels[k];  // labels in [0, C-2], never blank
    skip = (k >= 1) && (labels[k] != labels[k - 1]);
  }

  // --- main recursion: iter t computes alpha_t into alpha[t&1] ---
  for (int t0 = 0; t0 < TT; t0 += 4) {
#pragma unroll
    for (int u = 0; u < 4; ++u) {
      const int t = t0 + u;
      const int rb = u & 1;  // == t & 1
      const float rs = 1.0f / (partial[rb][0] + partial[rb][1]);

      {
        const float lp0 = __logf(rowbuf[rb][ext] * rs);
        const float lp1 = has2 ? __logf(rowbuf[rb][BLANK] * rs) : 0.0f;
        float a0, a1 = NEG_INF;
        if (t == 0) {
          a0 = (s < 2) ? lp0 : NEG_INF;
          // s=256 at t=0 stays NEG_INF
        } else {
          const float* ap_ = &alpha[rb ^ 1][2];
          const float as = ap_[s];
          const float apv = (s >= 1) ? ap_[s - 1] : NEG_INF;
          const float ak = skip ? ap_[s - 2] : NEG_INF;
          const float m = fmaxf(as, fmaxf(apv, ak));
          a0 = m + __logf(__expf(as - m) + __expf(apv - m) + __expf(ak - m)) +
               lp0;
          if (has2) {
            const float bs = ap_[256];
            const float bp = ap_[255];
            const float mm = fmaxf(bs, bp);
            a1 = mm + __logf(__expf(bs - mm) + __expf(bp - mm)) + lp1;
          }
        }
        alpha[rb][2 + s] = a0;
        if (has2) alpha[rb][2 + 256] = a1;
      }

      // stage row t+1 (register -> LDS, opposite buffer) + prefetch row t+5
      if (tid < CC && (t + 1 < TT)) {
        const float w = v[(u + 1) & 3];
        rowbuf[rb ^ 1][tid] = w;
        float x = w;
#pragma unroll
        for (int off = 32; off > 0; off >>= 1) x += __shfl_down(x, off);
        if ((tid & 63) == 0) partial[rb ^ 1][tid >> 6] = x;
        if (t + 5 < TT) v[(u + 1) & 3] = P[(size_t)(t + 5) * CC + tid] + EPSF;
      }
      barrier_lds_only();
    }
  }

  // --- epilogue: loglik = logaddexp(alpha[S-1], alpha[S-2]) ---
  if (tid == 0) {
    const float a1 = alpha[(TT - 1) & 1][2 + SS - 2];
    const float a2 = alpha[(TT - 1) & 1][2 + SS - 1];
    const float m = fmaxf(a1, a2);
    out[b] = -(m + __logf(__expf(a1 - m) + __expf(a2 - m)));
  }
}

extern "C" void kernel_launch(void* const* d_in, const int* in_sizes, int n_in,
                              void* d_out, int out_size, void* d_ws,
                              size_t ws_size, hipStream_t stream) {
  const int* yt = (const int*)d_in[0];
  const float* yp = (const float*)d_in[1];
  float* out = (float*)d_out;
  const int B = in_sizes[0] / LL;  // 128
  hipLaunchKernelGGL(ctc_kernel, dim3(B), dim3(256), 0, stream, yt, yp, out);
}

// Round 4
// 535.481 us; speedup vs baseline: 1.4644x; 1.4644x over previous
//
#include <hip/hip_runtime.h>

#define TT 1024
#define CC 128
#define LL 128
#define BLANK 127
#define NEGF (-1e30f)
#define EPSF 1e-7f
#define LN2F 0.69314718055994531f

// Raw gfx950 transcendental builtins (avoid glibc __exp2f/__log2f macro clash):
//   EXP2(x) = 2^x  (v_exp_f32),  LOG2(x) = log2(x)  (v_log_f32)
#define EXP2(x) __builtin_amdgcn_exp2f(x)
#define LOG2(x) __builtin_amdgcn_logf(x)

// log2-domain logsumexp. NEG_INF absorption matches the reference:
// if both args are -1e30, m=-1e30, deltas 0, result -1e30+1.0 == -1e30 (fp32
// absorbs); if one arg is -1e30 and m finite, exp2(-1e30-m) flushes to 0.
__device__ __forceinline__ float lse2_2(float x, float y) {
  const float m = fmaxf(x, y);
  return m + LOG2(EXP2(x - m) + EXP2(y - m));
}
__device__ __forceinline__ float lse2_3(float x, float y, float z) {
  const float m = fmaxf(x, fmaxf(y, z));
  return m + LOG2(EXP2(x - m) + EXP2(y - m) + EXP2(z - m));
}

// ---- prologue (parallel): RS[row] = 1 / sum_c (p[row,c] + eps) ----
// One wave per row; 4 rows per 256-thread block. Removes the row-sum
// reduction (6 dependent cross-lane ops ~600 cy) from the serial scan path.
__global__ __launch_bounds__(256) void rs_kernel(const float* __restrict__ yp,
                                                 float* __restrict__ rs) {
  const int lane = threadIdx.x & 63;
  const int row = blockIdx.x * 4 + (threadIdx.x >> 6);
  const float2 v = *(const float2*)(yp + (size_t)row * CC + lane * 2);
  float x = (v.x + EPSF) + (v.y + EPSF);
#pragma unroll
  for (int off = 32; off > 0; off >>= 1) x += __shfl_down(x, off);
  if (lane == 0) rs[row] = 1.0f / x;
}

// ---- serial scan: one wave per batch element, alpha in registers ----
// Lane L owns lattice states s = 4L..4L+3 (lane 63 additionally s=256).
// Per step the only cross-lane dependence is alpha[4L-1] = prev lane's a3
// (one __shfl_up). No LDS, no barriers. Emission probs gathered from
// global with a depth-4 register ring (prefetch distance ~4 steps).
__global__ __launch_bounds__(64) void scan_kernel(const int* __restrict__ yt,
                                                  const float* __restrict__ yp,
                                                  const float* __restrict__ rs,
                                                  float* __restrict__ out) {
  const int b = blockIdx.x;
  const int L = threadIdx.x & 63;
  const float* P = yp + (size_t)b * (TT * CC);
  const float* R = rs + b * TT;

  // labels[2L], labels[2L+1]; labels[2L-1] via shuffle (garbage on lane 0)
  const int2 lab = *(const int2*)(yt + b * LL + 2 * L);
  const int labm1 = __shfl_up(lab.y, 1);
  const bool skip1 = (L > 0) && (lab.x != labm1);  // s=4L+1 (k=2L)
  const bool skip3 = (lab.y != lab.x);             // s=4L+3 (k=2L+1)
  const bool lane0 = (L == 0);
  const int c1 = lab.x, c2 = lab.y;

  // prefetch ring: blank prob, two label probs, reciprocal row-sum
  float qb[4], q1[4], q2[4], rr[4];
#pragma unroll
  for (int j = 0; j < 4; ++j) {
    const float* Pj = P + j * CC;
    qb[j] = Pj[BLANK];
    q1[j] = Pj[c1];
    q2[j] = Pj[c2];
    rr[j] = R[j];
  }

  // virtual alpha_{-1}: only state 0 active at weight 1 (log2 = 0); the
  // t=0 loop step then produces exactly alpha0 = {lp[0], lp[1], NEG, ...}.
  float a0 = lane0 ? 0.0f : NEGF;
  float a1 = NEGF, a2 = NEGF, a3 = NEGF, a4 = NEGF;

  for (int t0 = 0; t0 < TT; t0 += 4) {
#pragma unroll
    for (int u = 0; u < 4; ++u) {
      const int t = t0 + u;
      // cross-lane: alpha[4L-1] = prev lane's a3
      float p3 = __shfl_up(a3, 1);
      if (lane0) p3 = NEGF;
      // emission log2-probs: log2((q+eps)*r) = log2(fma(q, r, eps*r))
      const float r = rr[u], er = r * EPSF;
      const float lpb = LOG2(__builtin_fmaf(qb[u], r, er));
      const float lp1 = LOG2(__builtin_fmaf(q1[u], r, er));
      const float lp2v = LOG2(__builtin_fmaf(q2[u], r, er));
      // refill ring with row t+4
      if (t + 4 < TT) {
        const float* Pn = P + (size_t)(t + 4) * CC;
        qb[u] = Pn[BLANK];
        q1[u] = Pn[c1];
        q2[u] = Pn[c2];
        rr[u] = R[t + 4];
      }
      // state updates (even states: no skip; odd states: optional skip)
      const float n0 = lse2_2(a0, p3) + lpb;                      // s=4L
      const float n1 = lse2_3(a1, a0, skip1 ? p3 : NEGF) + lp1;   // s=4L+1
      const float n2 = lse2_2(a2, a1) + lpb;                      // s=4L+2
      const float n3 = lse2_3(a3, a2, skip3 ? a1 : NEGF) + lp2v;  // s=4L+3
      const float n4 = lse2_2(a4, a3) + lpb;  // s=256 (lane 63 only)
      a0 = n0; a1 = n1; a2 = n2; a3 = n3; a4 = n4;
    }
  }

  // loglik = logaddexp(alpha[255], alpha[256]) = ln2 * lse2(a3, a4) on lane 63
  if (L == 63) out[b] = -LN2F * lse2_2(a4, a3);
}

extern "C" void kernel_launch(void* const* d_in, const int* in_sizes, int n_in,
                              void* d_out, int out_size, void* d_ws,
                              size_t ws_size, hipStream_t stream) {
  const int* yt = (const int*)d_in[0];
  const float* yp = (const float*)d_in[1];
  float* out = (float*)d_out;
  float* rsbuf = (float*)d_ws;     // B*T floats = 512 KB
  const int B = in_sizes[0] / LL;  // 128
  hipLaunchKernelGGL(rs_kernel, dim3((B * TT) / 4), dim3(256), 0, stream, yp,
                     rsbuf);
  hipLaunchKernelGGL(scan_kernel, dim3(B), dim3(64), 0, stream, yt, yp, rsbuf,
                     out);
}

// Round 7
// 193.540 us; speedup vs baseline: 4.0517x; 2.7668x over previous
//
#include <hip/hip_runtime.h>

#define TT 1024
#define CC 128
#define LL 128
#define EPSF 1e-7f
#define LN2F 0.69314718055994531f

#define LOG2F(x) __builtin_amdgcn_logf(x)

typedef unsigned int uint;

template <int CTRL>
__device__ __forceinline__ int dpp_i(int old_, int x) {
  return __builtin_amdgcn_update_dpp(old_, x, CTRL, 0xf, 0xf, false);
}
// shift a3 to next lane (wave_shr:1); lane 0 receives 0.0 via old-value
__device__ __forceinline__ double dpp_shr1_f64(double x) {
  const int lo = __double2loint(x), hi = __double2hiint(x);
  return __hiloint2double(dpp_i<0x138>(0, hi), dpp_i<0x138>(0, lo));
}

// compile-time component select (k is an unroll constant -> folds to a reg)
__device__ __forceinline__ uint uc(const uint4& e, int k) {
  return k == 0 ? e.x : k == 1 ? e.y : k == 2 ? e.z : e.w;
}
__device__ __forceinline__ float fc(const float4& e, int k) {
  return k == 0 ? e.x : k == 1 ? e.y : k == 2 ? e.z : e.w;
}
// fp32 -> bf16 bits, round-to-nearest-even (inputs finite positive)
__device__ __forceinline__ uint bf16bits(float x) {
  uint u = __float_as_uint(x);
  return (u + 0x7fffu + ((u >> 16) & 1u)) >> 16;
}

// ---- prep (parallel): normalized emission probs, transposed for the scan ----
// Block = 512 threads = 8 waves; block handles (b, 8 consecutive t).
//   ET[b][L][t] (uint: lo16=bf16 p[lab 2L], hi16=bf16 p[lab 2L+1])
//   EB[b][t]    (fp32 blank prob)
__global__ __launch_bounds__(512) void prep_kernel(const int* __restrict__ yt,
                                                   const float* __restrict__ yp,
                                                   uint* __restrict__ ET,
                                                   float* __restrict__ EB) {
  const int tid = threadIdx.x;
  const int w = tid >> 6;  // wave 0..7
  const int L = tid & 63;
  const int b = blockIdx.x >> 7;
  const int tg = blockIdx.x & 127;
  const int t = tg * 8 + w;

  __shared__ float rowp[8][130];  // normalized probs per wave-row
  __shared__ uint tp[64][9];      // [L][w] transpose buffer (+1 pad)

  const float* P = yp + ((size_t)b * TT + t) * CC;
  const float2 v = *(const float2*)(P + 2 * L);
  float x = (v.x + EPSF) + (v.y + EPSF);
#pragma unroll
  for (int off = 32; off > 0; off >>= 1) x += __shfl_xor(x, off);
  const float r = 1.0f / x;
  const float er = EPSF * r;
  *(float2*)&rowp[w][2 * L] =
      make_float2(__builtin_fmaf(v.x, r, er), __builtin_fmaf(v.y, r, er));
  const int2 lab = *(const int2*)(yt + b * LL + 2 * L);
  if (L == 63) EB[b * TT + t] = __builtin_fmaf(v.y, r, er);  // c=127 blank
  __syncthreads();  // rowp visible (belt & suspenders; same-wave RAW anyway)
  const float p1 = rowp[w][lab.x];
  const float p2 = rowp[w][lab.y];
  tp[L][w] = (bf16bits(p2) << 16) | bf16bits(p1);
  __syncthreads();
  const int Lo = tid >> 3, s = tid & 7;
  ET[((size_t)(b * 64 + Lo) << 10) + tg * 8 + s] = tp[Lo][s];
}

// ---- serial scan: fp64 linear-domain scaled forward, one wave per b ----
// Lane L owns states 4L..4L+3 (a4 mirrors next lane's a0; lane63's a4 is
// state 256). alpha_true = a * 2^ell with wave-uniform ell. fp64 state +
// rescale-to-2^511 every 8 steps preserves ~1534 bits (~1063 nats) of range
// below the running max — fp32's 126-bit window lost terminal-path mass
// (round 6: absmax ~96-454 nats). Per step: 2 DPP moves + ~12 f64 VALU,
// no transcendentals, no DS ops. Emissions stream via a branchless 32-step
// register ring (dwordx4 loads).
__global__ __launch_bounds__(64) void scan_kernel(const int* __restrict__ yt,
                                                  const uint* __restrict__ ET,
                                                  const float* __restrict__ EB,
                                                  float* __restrict__ out) {
  const int b = blockIdx.x;
  const int L = threadIdx.x & 63;

  const int2 lab = *(const int2*)(yt + b * LL + 2 * L);
  const int labm1 = __shfl_up(lab.y, 1);
  const bool skip1 = (L > 0) && (lab.x != labm1);  // s=4L+1
  const bool skip3 = (lab.y != lab.x);             // s=4L+3

  const uint* Ep = ET + ((size_t)(b * 64 + L) << 10);
  const float* Bp = EB + b * TT;

  uint4 et[4][2];
  float4 eb[4][2];
#pragma unroll
  for (int g = 0; g < 4; ++g) {
    et[g][0] = *(const uint4*)(Ep + g * 8);
    et[g][1] = *(const uint4*)(Ep + g * 8 + 4);
    eb[g][0] = *(const float4*)(Bp + g * 8);
    eb[g][1] = *(const float4*)(Bp + g * 8 + 4);
  }

  // virtual alpha_{-1}: state 0 = 1, rest 0; first loop step yields alpha_0
  double a0 = (L == 0) ? 1.0 : 0.0;
  double a1 = 0.0, a2 = 0.0, a3 = 0.0, a4 = 0.0;
  int ell = 0;  // wave-uniform: alpha_true = a * 2^ell

#pragma unroll 1
  for (int tb = 0; tb < TT; tb += 32) {
#pragma unroll
    for (int g = 0; g < 4; ++g) {
#pragma unroll
      for (int u = 0; u < 8; ++u) {
        const uint wv = uc(et[g][u >> 2], u & 3);
        const double p1 = (double)__uint_as_float(wv << 16);
        const double p2 = (double)__uint_as_float(wv & 0xffff0000u);
        const double pb = (double)fc(eb[g][u >> 2], u & 3);
        const double p3 = dpp_shr1_f64(a3);  // alpha[4L-1]; lane0 -> 0
        const double z1 = skip1 ? p3 : 0.0;
        const double z3 = skip3 ? a1 : 0.0;
        const double n0 = (a0 + p3) * pb;
        const double n1 = (a1 + a0 + z1) * p1;
        const double n2 = (a2 + a1) * pb;
        const double n3 = (a3 + a2 + z3) * p2;
        const double n4 = (a4 + a3) * pb;
        a0 = n0; a1 = n1; a2 = n2; a3 = n3; a4 = n4;
      }
      // wave-uniform rescale every 8 steps: put max at 2^511.
      // Reduce the f64 exponent field (int) via DPP; lane 63 holds wave max.
      const double m = fmax(fmax(fmax(a0, a1), fmax(a2, a3)), a4);
      int ke = (__double2hiint(m) >> 20) & 0x7ff;
      ke = max(ke, dpp_i<0x111>(ke, ke));  // row_shr:1
      ke = max(ke, dpp_i<0x112>(ke, ke));  // row_shr:2
      ke = max(ke, dpp_i<0x114>(ke, ke));  // row_shr:4
      ke = max(ke, dpp_i<0x118>(ke, ke));  // row_shr:8
      ke = max(ke, dpp_i<0x142>(ke, ke));  // row_bcast:15
      ke = max(ke, dpp_i<0x143>(ke, ke));  // row_bcast:31
      ke = __builtin_amdgcn_readlane(ke, 63);
      const int e = ke - 1534;  // = unbiased_exp(max) - 511
      const double sc = __hiloint2double((1023 - e) << 20, 0);  // 2^{-e}
      a0 *= sc; a1 *= sc; a2 *= sc; a3 *= sc; a4 *= sc;
      ell += e;
      // refill group g for t = tb + g*8 + 32 (clamped; branchless)
      const int tl = min(tb + g * 8 + 32, TT - 8);
      et[g][0] = *(const uint4*)(Ep + tl);
      et[g][1] = *(const uint4*)(Ep + tl + 4);
      eb[g][0] = *(const float4*)(Bp + tl);
      eb[g][1] = *(const float4*)(Bp + tl + 4);
    }
  }

  if (L == 63) {
    // states 255 (=a3), 256 (=a4): loglik = ln2 * (ell + log2(a3+a4))
    double s = a3 + a4;
    if (s < 2.3e-308) s = 2.3e-308;  // stay normal; loud-but-finite floor
    const int es = ((__double2hiint(s) >> 20) & 0x7ff) - 1023;
    const double mant = s * __hiloint2double((1023 - es) << 20, 0);  // [1,2)
    out[b] = -LN2F * ((float)(ell + es) + LOG2F((float)mant));
  }
}

extern "C" void kernel_launch(void* const* d_in, const int* in_sizes, int n_in,
                              void* d_out, int out_size, void* d_ws,
                              size_t ws_size, hipStream_t stream) {
  const int* yt = (const int*)d_in[0];
  const float* yp = (const float*)d_in[1];
  float* out = (float*)d_out;
  const int B = in_sizes[0] / LL;  // 128
  uint* ET = (uint*)d_ws;                                       // 32 MiB
  float* EB = (float*)((char*)d_ws + (size_t)B * 64 * TT * 4);  // +512 KiB
  hipLaunchKernelGGL(prep_kernel, dim3(B * 128), dim3(512), 0, stream, yt, yp,
                     ET, EB);
  hipLaunchKernelGGL(scan_kernel, dim3(B), dim3(64), 0, stream, yt, ET, EB,
                     out);
}

// Round 8
// 180.515 us; speedup vs baseline: 4.3441x; 1.0722x over previous
//
#include <hip/hip_runtime.h>

#define TT 1024
#define CC 128
#define LL 128
#define EPSF 1e-7f
#define LN2F 0.69314718055994531f

#define LOG2F(x) __builtin_amdgcn_logf(x)

typedef unsigned int uint;

template <int CTRL>
__device__ __forceinline__ int dpp_i(int old_, int x) {
  return __builtin_amdgcn_update_dpp(old_, x, CTRL, 0xf, 0xf, false);
}
// shift a3 to next lane (wave_shr:1); lane 0 receives 0.0 via old-value
__device__ __forceinline__ double dpp_shr1_f64(double x) {
  const int lo = __double2loint(x), hi = __double2hiint(x);
  return __hiloint2double(dpp_i<0x138>(0, hi), dpp_i<0x138>(0, lo));
}

// compile-time component select (k is an unroll constant -> folds to a reg)
__device__ __forceinline__ uint uc(const uint4& e, int k) {
  return k == 0 ? e.x : k == 1 ? e.y : k == 2 ? e.z : e.w;
}
__device__ __forceinline__ float fc(const float4& e, int k) {
  return k == 0 ? e.x : k == 1 ? e.y : k == 2 ? e.z : e.w;
}
// fp32 -> bf16 bits, round-to-nearest-even (inputs finite positive)
__device__ __forceinline__ uint bf16bits(float x) {
  uint u = __float_as_uint(x);
  return (u + 0x7fffu + ((u >> 16) & 1u)) >> 16;
}

// ---- prep (parallel): normalized emission probs, transposed for the scan ----
// Block = 512 threads = 8 waves; block handles (b, 8 consecutive t).
//   ET[b][t4][L] (uint4 over t within group-of-4: bf16 p[lab 2L] | p[lab 2L+1])
//     -> scan's per-lane dwordx4 is a single contiguous 1KB wave transaction
//   EB[b][t] (fp32 blank prob)
__global__ __launch_bounds__(512) void prep_kernel(const int* __restrict__ yt,
                                                   const float* __restrict__ yp,
                                                   uint* __restrict__ ET,
                                                   float* __restrict__ EB) {
  const int tid = threadIdx.x;
  const int w = tid >> 6;  // wave 0..7
  const int L = tid & 63;
  const int b = blockIdx.x >> 7;
  const int tg = blockIdx.x & 127;
  const int t = tg * 8 + w;

  __shared__ float rowp[8][130];  // normalized probs per wave-row
  __shared__ uint tp[64][9];      // [L][w] transpose buffer (+1 pad)

  const float* P = yp + ((size_t)b * TT + t) * CC;
  const float2 v = *(const float2*)(P + 2 * L);
  float x = (v.x + EPSF) + (v.y + EPSF);
#pragma unroll
  for (int off = 32; off > 0; off >>= 1) x += __shfl_xor(x, off);
  const float r = 1.0f / x;
  const float er = EPSF * r;
  *(float2*)&rowp[w][2 * L] =
      make_float2(__builtin_fmaf(v.x, r, er), __builtin_fmaf(v.y, r, er));
  const int2 lab = *(const int2*)(yt + b * LL + 2 * L);
  if (L == 63) EB[b * TT + t] = __builtin_fmaf(v.y, r, er);  // c=127 blank
  __syncthreads();
  const float p1 = rowp[w][lab.x];
  const float p2 = rowp[w][lab.y];
  tp[L][w] = (bf16bits(p2) << 16) | bf16bits(p1);
  __syncthreads();
  if (tid < 128) {  // 2 t4-groups x 64 lanes, coalesced uint4 stores
    const int g4 = tid >> 6, Lo = tid & 63;
    uint4 val;
    val.x = tp[Lo][g4 * 4 + 0];
    val.y = tp[Lo][g4 * 4 + 1];
    val.z = tp[Lo][g4 * 4 + 2];
    val.w = tp[Lo][g4 * 4 + 3];
    ((uint4*)ET)[((size_t)(b * 256 + tg * 2 + g4) << 6) + Lo] = val;
  }
}

// ---- serial scan: fp64 linear-domain scaled forward, one wave per b ----
// Lane L owns states 4L..4L+3 (a4 mirrors next lane's a0; lane63's a4 is
// state 256). alpha_true = a * 2^ell, wave-uniform ell. Rescale-to-2^511
// every 16 steps (worst-case decay 16*30=480 bits -> max >= 2^31; preserved
// depth below max ~730 nats; worst growth 3^16 -> <= 2^537: safe both ways).
// Skip transitions folded as fma with s1d/s3d in {0.0,1.0} (no cndmasks).
// Per step: 2 int DPP + 3 cvt + 13 f64 VALU. Emissions stream via a
// branchless 32-step register ring (coalesced dwordx4 loads).
__global__ __launch_bounds__(64) void scan_kernel(const int* __restrict__ yt,
                                                  const uint* __restrict__ ET,
                                                  const float* __restrict__ EB,
                                                  float* __restrict__ out) {
  const int b = blockIdx.x;
  const int L = threadIdx.x & 63;

  const int2 lab = *(const int2*)(yt + b * LL + 2 * L);
  const int labm1 = __shfl_up(lab.y, 1);
  const double s1d = ((L > 0) && (lab.x != labm1)) ? 1.0 : 0.0;  // s=4L+1
  const double s3d = (lab.y != lab.x) ? 1.0 : 0.0;               // s=4L+3

  const uint4* Et = (const uint4*)ET + ((size_t)b << 14) + L;  // [t4][64]
  const float* Bp = EB + b * TT;

  uint4 et[8];
  float4 eb[8];
#pragma unroll
  for (int g = 0; g < 8; ++g) {
    et[g] = Et[g * 64];
    eb[g] = *(const float4*)(Bp + g * 4);
  }

  // virtual alpha_{-1}: state 0 = 1, rest 0; first loop step yields alpha_0
  double a0 = (L == 0) ? 1.0 : 0.0;
  double a1 = 0.0, a2 = 0.0, a3 = 0.0, a4 = 0.0;
  int ell = 0;  // wave-uniform: alpha_true = a * 2^ell

#pragma unroll 1
  for (int tb = 0; tb < TT; tb += 32) {
#pragma unroll
    for (int g = 0; g < 8; ++g) {
#pragma unroll
      for (int u = 0; u < 4; ++u) {
        const uint wv = uc(et[g], u);
        const double p1 = (double)__uint_as_float(wv << 16);
        const double p2 = (double)__uint_as_float(wv & 0xffff0000u);
        const double pb = (double)fc(eb[g], u);
        const double p3 = dpp_shr1_f64(a3);  // alpha[4L-1]; lane0 -> 0
        const double n0 = (a0 + p3) * pb;
        const double n1 = fma(s1d, p3, a0 + a1) * p1;
        const double n2 = (a2 + a1) * pb;
        const double n3 = fma(s3d, a1, a3 + a2) * p2;
        const double n4 = (a4 + a3) * pb;
        a0 = n0; a1 = n1; a2 = n2; a3 = n3; a4 = n4;
      }
      // refill group g for t4 = tb/4 + 8 + g (clamped; wave-uniform addr)
      const int t4n = min(tb / 4 + 8 + g, 255);
      et[g] = Et[(size_t)t4n * 64];
      eb[g] = *(const float4*)(Bp + t4n * 4);
      if ((g & 3) == 3) {  // wave-uniform rescale every 16 steps
        const double m = fmax(fmax(fmax(a0, a1), fmax(a2, a3)), a4);
        int ke = (__double2hiint(m) >> 20) & 0x7ff;
        ke = max(ke, dpp_i<0x111>(ke, ke));  // row_shr:1
        ke = max(ke, dpp_i<0x112>(ke, ke));  // row_shr:2
        ke = max(ke, dpp_i<0x114>(ke, ke));  // row_shr:4
        ke = max(ke, dpp_i<0x118>(ke, ke));  // row_shr:8
        ke = max(ke, dpp_i<0x142>(ke, ke));  // row_bcast:15
        ke = max(ke, dpp_i<0x143>(ke, ke));  // row_bcast:31
        ke = __builtin_amdgcn_readlane(ke, 63);
        const int e = ke - 1534;  // unbiased_exp(max) - 511
        const double sc = __hiloint2double((1023 - e) << 20, 0);  // 2^{-e}
        a0 *= sc; a1 *= sc; a2 *= sc; a3 *= sc; a4 *= sc;
        ell += e;
      }
    }
  }

  if (L == 63) {
    // states 255 (=a3), 256 (=a4): loglik = ln2 * (ell + log2(a3+a4))
    double s = a3 + a4;
    if (s < 2.3e-308) s = 2.3e-308;  // stay normal; loud-but-finite floor
    const int es = ((__double2hiint(s) >> 20) & 0x7ff) - 1023;
    const double mant = s * __hiloint2double((1023 - es) << 20, 0);  // [1,2)
    out[b] = -LN2F * ((float)(ell + es) + LOG2F((float)mant));
  }
}

extern "C" void kernel_launch(void* const* d_in, const int* in_sizes, int n_in,
                              void* d_out, int out_size, void* d_ws,
                              size_t ws_size, hipStream_t stream) {
  const int* yt = (const int*)d_in[0];
  const float* yp = (const float*)d_in[1];
  float* out = (float*)d_out;
  const int B = in_sizes[0] / LL;  // 128
  uint* ET = (uint*)d_ws;                                       // 33.55 MB
  float* EB = (float*)((char*)d_ws + (size_t)B * 64 * TT * 4);  // +512 KB
  hipLaunchKernelGGL(prep_kernel, dim3(B * 128), dim3(512), 0, stream, yt, yp,
                     ET, EB);
  hipLaunchKernelGGL(scan_kernel, dim3(B), dim3(64), 0, stream, yt, ET, EB,
                     out);
}

// Round 9
// 169.596 us; speedup vs baseline: 4.6237x; 1.0644x over previous
//
#include <hip/hip_runtime.h>

#define TT 1024
#define CC 128
#define LL 128
#define EPSF 1e-7f
#define LN2F 0.69314718055994531f

#define LOG2F(x) __builtin_amdgcn_logf(x)

typedef unsigned int uint;

template <int CTRL>
__device__ __forceinline__ int dpp_i(int old_, int x) {
  return __builtin_amdgcn_update_dpp(old_, x, CTRL, 0xf, 0xf, false);
}
// shift a3 to next lane (wave_shr:1); lane 0 receives 0.0 via old-value
__device__ __forceinline__ double dpp_shr1_f64(double x) {
  const int lo = __double2loint(x), hi = __double2hiint(x);
  return __hiloint2double(dpp_i<0x138>(0, hi), dpp_i<0x138>(0, lo));
}

// fp32 -> bf16 bits, round-to-nearest-even (inputs finite positive)
__device__ __forceinline__ uint bf16bits(float x) {
  uint u = __float_as_uint(x);
  return (u + 0x7fffu + ((u >> 16) & 1u)) >> 16;
}

// ---- prep (parallel): normalized emission probs, transposed for the scan ----
// Block = 512 threads = 8 waves; block handles (b, 8 consecutive t).
//   ET[b][t4][L] (uint4 over t in group-of-4: bf16 p[lab 2L] | p[lab 2L+1])
//   EB[b][t] (fp32 blank prob)
__global__ __launch_bounds__(512) void prep_kernel(const int* __restrict__ yt,
                                                   const float* __restrict__ yp,
                                                   uint* __restrict__ ET,
                                                   float* __restrict__ EB) {
  const int tid = threadIdx.x;
  const int w = tid >> 6;  // wave 0..7
  const int L = tid & 63;
  const int b = blockIdx.x >> 7;
  const int tg = blockIdx.x & 127;
  const int t = tg * 8 + w;

  __shared__ float rowp[8][130];  // normalized probs per wave-row
  __shared__ uint tp[64][9];      // [L][w] transpose buffer (+1 pad)

  const float* P = yp + ((size_t)b * TT + t) * CC;
  const float2 v = *(const float2*)(P + 2 * L);
  float x = (v.x + EPSF) + (v.y + EPSF);
#pragma unroll
  for (int off = 32; off > 0; off >>= 1) x += __shfl_xor(x, off);
  const float r = 1.0f / x;
  const float er = EPSF * r;
  *(float2*)&rowp[w][2 * L] =
      make_float2(__builtin_fmaf(v.x, r, er), __builtin_fmaf(v.y, r, er));
  const int2 lab = *(const int2*)(yt + b * LL + 2 * L);
  if (L == 63) EB[b * TT + t] = __builtin_fmaf(v.y, r, er);  // c=127 blank
  __syncthreads();
  const float p1 = rowp[w][lab.x];
  const float p2 = rowp[w][lab.y];
  tp[L][w] = (bf16bits(p2) << 16) | bf16bits(p1);
  __syncthreads();
  if (tid < 128) {  // 2 t4-groups x 64 lanes, coalesced uint4 stores
    const int g4 = tid >> 6, Lo = tid & 63;
    uint4 val;
    val.x = tp[Lo][g4 * 4 + 0];
    val.y = tp[Lo][g4 * 4 + 1];
    val.z = tp[Lo][g4 * 4 + 2];
    val.w = tp[Lo][g4 * 4 + 3];
    ((uint4*)ET)[((size_t)(b * 256 + tg * 2 + g4) << 6) + Lo] = val;
  }
}

// ---- serial scan: fp64 linear-domain scaled forward, one wave per b ----
// Lane L owns states 4L..4L+3 (lane63's extra a4 is state 256). alpha_true =
// a * 2^ell, wave-uniform ell; rescale-to-2^511 every 16 steps. The 32-step
// emission ring lives in 16 NAMED uint4/float4 variables — round 7/8 used
// arrays, which the compiler demoted to scratch (VGPR_Count=44 < ring size;
// per-step dependent scratch round-trips = the ~162 cy/step plateau, proven
// by equal dur at 17MB vs 0MB HBM fetch).

// one lattice step using word wv (bf16 pair) and blank prob pbf
#define CTC_STEP(wv, pbf)                                          \
  do {                                                             \
    const double p1 = (double)__uint_as_float((wv) << 16);         \
    const double p2 = (double)__uint_as_float((wv) & 0xffff0000u); \
    const double pb = (double)(pbf);                               \
    const double p3 = dpp_shr1_f64(a3);                            \
    const double n0 = (a0 + p3) * pb;                              \
    const double n1 = fma(s1d, p3, a0 + a1) * p1;                  \
    const double n2 = (a2 + a1) * pb;                              \
    const double n3 = fma(s3d, a1, a3 + a2) * p2;                  \
    const double n4 = (a4 + a3) * pb;                              \
    a0 = n0; a1 = n1; a2 = n2; a3 = n3; a4 = n4;                   \
  } while (0)

#define CTC_GROUP(g)                           \
  do {                                         \
    CTC_STEP(et##g.x, eb##g.x);                \
    CTC_STEP(et##g.y, eb##g.y);                \
    CTC_STEP(et##g.z, eb##g.z);                \
    CTC_STEP(et##g.w, eb##g.w);                \
    const int t4n = min(tb4 + 8 + g, 255);     \
    et##g = Et[(size_t)t4n * 64];              \
    eb##g = *(const float4*)(Bp + t4n * 4);    \
  } while (0)

#define CTC_RESCALE()                                             \
  do {                                                            \
    const double m = fmax(fmax(fmax(a0, a1), fmax(a2, a3)), a4);  \
    int ke = (__double2hiint(m) >> 20) & 0x7ff;                   \
    ke = max(ke, dpp_i<0x111>(ke, ke));                           \
    ke = max(ke, dpp_i<0x112>(ke, ke));                           \
    ke = max(ke, dpp_i<0x114>(ke, ke));                           \
    ke = max(ke, dpp_i<0x118>(ke, ke));                           \
    ke = max(ke, dpp_i<0x142>(ke, ke));                           \
    ke = max(ke, dpp_i<0x143>(ke, ke));                           \
    ke = __builtin_amdgcn_readlane(ke, 63);                       \
    const int e = ke - 1534; /* unbiased_exp(max) - 511 */        \
    const double sc = __hiloint2double((1023 - e) << 20, 0);      \
    a0 *= sc; a1 *= sc; a2 *= sc; a3 *= sc; a4 *= sc;             \
    ell += e;                                                     \
  } while (0)

__global__ __launch_bounds__(64) void scan_kernel(const int* __restrict__ yt,
                                                  const uint* __restrict__ ET,
                                                  const float* __restrict__ EB,
                                                  float* __restrict__ out) {
  const int b = blockIdx.x;
  const int L = threadIdx.x & 63;

  const int2 lab = *(const int2*)(yt + b * LL + 2 * L);
  const int labm1 = __shfl_up(lab.y, 1);
  const double s1d = ((L > 0) && (lab.x != labm1)) ? 1.0 : 0.0;  // s=4L+1
  const double s3d = (lab.y != lab.x) ? 1.0 : 0.0;               // s=4L+3

  const uint4* Et = (const uint4*)ET + ((size_t)b << 14) + L;  // [t4][64]
  const float* Bp = EB + b * TT;

  uint4 et0 = Et[0 * 64], et1 = Et[1 * 64], et2 = Et[2 * 64], et3 = Et[3 * 64];
  uint4 et4 = Et[4 * 64], et5 = Et[5 * 64], et6 = Et[6 * 64], et7 = Et[7 * 64];
  float4 eb0 = *(const float4*)(Bp + 0), eb1 = *(const float4*)(Bp + 4);
  float4 eb2 = *(const float4*)(Bp + 8), eb3 = *(const float4*)(Bp + 12);
  float4 eb4 = *(const float4*)(Bp + 16), eb5 = *(const float4*)(Bp + 20);
  float4 eb6 = *(const float4*)(Bp + 24), eb7 = *(const float4*)(Bp + 28);

  // virtual alpha_{-1}: state 0 = 1, rest 0; first loop step yields alpha_0
  double a0 = (L == 0) ? 1.0 : 0.0;
  double a1 = 0.0, a2 = 0.0, a3 = 0.0, a4 = 0.0;
  int ell = 0;  // wave-uniform: alpha_true = a * 2^ell

#pragma unroll 1
  for (int tb4 = 0; tb4 < TT / 4; tb4 += 8) {
    CTC_GROUP(0);
    CTC_GROUP(1);
    CTC_GROUP(2);
    CTC_GROUP(3);
    CTC_RESCALE();
    CTC_GROUP(4);
    CTC_GROUP(5);
    CTC_GROUP(6);
    CTC_GROUP(7);
    CTC_RESCALE();
  }

  if (L == 63) {
    // states 255 (=a3), 256 (=a4): loglik = ln2 * (ell + log2(a3+a4))
    double s = a3 + a4;
    if (s < 2.3e-308) s = 2.3e-308;  // stay normal; loud-but-finite floor
    const int es = ((__double2hiint(s) >> 20) & 0x7ff) - 1023;
    const double mant = s * __hiloint2double((1023 - es) << 20, 0);  // [1,2)
    out[b] = -LN2F * ((float)(ell + es) + LOG2F((float)mant));
  }
}

extern "C" void kernel_launch(void* const* d_in, const int* in_sizes, int n_in,
                              void* d_out, int out_size, void* d_ws,
                              size_t ws_size, hipStream_t stream) {
  const int* yt = (const int*)d_in[0];
  const float* yp = (const float*)d_in[1];
  float* out = (float*)d_out;
  const int B = in_sizes[0] / LL;  // 128
  uint* ET = (uint*)d_ws;                                       // 33.55 MB
  float* EB = (float*)((char*)d_ws + (size_t)B * 64 * TT * 4);  // +512 KB
  hipLaunchKernelGGL(prep_kernel, dim3(B * 128), dim3(512), 0, stream, yt, yp,
                     ET, EB);
  hipLaunchKernelGGL(scan_kernel, dim3(B), dim3(64), 0, stream, yt, ET, EB,
                     out);
}